// Round 4
// baseline (1802.254 us; speedup 1.0000x reference)
//
#include <hip/hip_runtime.h>
#include <cstdint>
#include <cstddef>

#define SEQ 32768
#define DIM 1024
#define HID 128
#define KMAXV 103   // int(0.1*1024)+1

using f4 = __attribute__((ext_vector_type(4))) float;
using f2 = __attribute__((ext_vector_type(2))) float;

// ---------------------------------------------------------------------------
// Kernel A: per-block partial column sums of x (f64, deterministic order).
// ---------------------------------------------------------------------------
__global__ __launch_bounds__(256) void pool_partial(const float* __restrict__ x,
                                                    double* __restrict__ part) {
    const int b = blockIdx.x;
    const int t = threadIdx.x;
    const int r0 = b * 128;
    double s0 = 0.0, s1 = 0.0, s2 = 0.0, s3 = 0.0;
    for (int r = 0; r < 128; ++r) {
        const float* row = x + (size_t)(r0 + r) * DIM;
        s0 += (double)row[t];
        s1 += (double)row[t + 256];
        s2 += (double)row[t + 512];
        s3 += (double)row[t + 768];
    }
    double* p = part + (size_t)b * DIM;
    p[t] = s0; p[t + 256] = s1; p[t + 512] = s2; p[t + 768] = s3;
}

// ---------------------------------------------------------------------------
// Kernel B: finish pooling, complexity net (exact erf GELU, sigmoid), k.
// ---------------------------------------------------------------------------
__global__ __launch_bounds__(1024) void tiny_net(const double* __restrict__ part,
                                                 const float* __restrict__ w1,
                                                 const float* __restrict__ b1,
                                                 const float* __restrict__ w2,
                                                 const float* __restrict__ b2,
                                                 float* __restrict__ out_scalars,
                                                 int* __restrict__ kout) {
    __shared__ double pooled[DIM];
    __shared__ double hidv[HID];
    const int t = threadIdx.x;

    double s = 0.0;
    for (int b = 0; b < 256; ++b) s += part[(size_t)b * DIM + t];
    pooled[t] = s / (double)SEQ;
    __syncthreads();

    if (t < HID) {
        double h = (double)b1[t];
        for (int d = 0; d < DIM; ++d) h += pooled[d] * (double)w1[d * HID + t];
        h = 0.5 * h * (1.0 + erf(h * 0.70710678118654752440));
        hidv[t] = h;
    }
    __syncthreads();

    if (t == 0) {
        double z = (double)b2[0];
        for (int j = 0; j < HID; ++j) z += hidv[j] * (double)w2[j];
        double c = 1.0 / (1.0 + exp(-z));
        double ar = 0.01 + 0.09 * c;
        int k = (int)(ar * (double)DIM);  // trunc
        if (k < 1) k = 1;
        if (k > KMAXV) k = KMAXV;
        out_scalars[0] = (float)c;
        out_scalars[1] = (float)ar;
        out_scalars[2] = (float)k;
        *kout = k;
    }
}

// ---------------------------------------------------------------------------
// Kernel C: importance GEMM with numpy/OpenBLAS f32 semantics — NUMERICS
// FROZEN: per element, sequential-k fmaf within panels {384,320,320}, panel
// sums added in order ((P1+P2)+P3). Identical per-element op order to the
// round-2/3 passing kernels.
// Structure: 512 threads; thread t owns ALL 16 rows x 2 contiguous cols
// (c2=2t) -> wg k-rows read exactly once per block (dwordx2, coalesced),
// x-tile staged once in LDS (64 KB), read as wave-broadcast ds_read_b128.
// No launch_bounds occupancy hint: LDS caps residency at 2 blocks/CU; the
// compiler gets free rein on VGPRs (working set ~100) to avoid spill moves.
// Then exact per-row dynamic-k threshold (tie-inclusive >=) via u32 radix
// search, float4 coalesced output.
// ---------------------------------------------------------------------------
#define BM 16
#define CBLOCK 512

__global__ __launch_bounds__(CBLOCK) void gate_kernel(const float* __restrict__ x,
                                                      const float* __restrict__ wg,
                                                      const float* __restrict__ bg,
                                                      const float* __restrict__ rm,
                                                      const float* __restrict__ rv,
                                                      const int* __restrict__ kptr,
                                                      float* __restrict__ out) {
    __shared__ float xs[BM][DIM];                 // 64 KB; selbuf aliases after GEMM
    float (*selbuf)[DIM] = (float (*)[DIM])xs;

    const int t = threadIdx.x;
    const int c2 = t << 1;           // 2 contiguous columns c2, c2+1
    const int row0 = blockIdx.x * BM;

    // stage full x-tile (coalesced float4)
    {
        const f4* xg = (const f4*)(x + (size_t)row0 * DIM);
        f4* xl = (f4*)xs;
        for (int i = t; i < BM * (DIM / 4); i += CBLOCK) xl[i] = xg[i];
    }
    __syncthreads();

    float dot[16][2];
#pragma unroll
    for (int m = 0; m < 16; ++m) { dot[m][0] = 0.0f; dot[m][1] = 0.0f; }

    const int pb[4] = {0, 384, 704, 1024};       // OpenBLAS K-panels
    const float* wbase = wg + c2;

    for (int p = 0; p < 3; ++p) {
        float pacc[16][2];
#pragma unroll
        for (int m = 0; m < 16; ++m) { pacc[m][0] = 0.0f; pacc[m][1] = 0.0f; }

        for (int kk0 = pb[p]; kk0 < pb[p + 1]; kk0 += 4) {
            const f2 w0 = *(const f2*)(wbase + (size_t)(kk0 + 0) * DIM);
            const f2 w1v = *(const f2*)(wbase + (size_t)(kk0 + 1) * DIM);
            const f2 w2v = *(const f2*)(wbase + (size_t)(kk0 + 2) * DIM);
            const f2 w3v = *(const f2*)(wbase + (size_t)(kk0 + 3) * DIM);
#pragma unroll
            for (int m = 0; m < 16; ++m) {
                const f4 xv = *(const f4*)(&xs[m][kk0]);   // broadcast ds_read_b128
                float a0 = pacc[m][0], a1 = pacc[m][1];
                a0 = fmaf(xv[0], w0[0], a0);  a1 = fmaf(xv[0], w0[1], a1);   // k=kk0
                a0 = fmaf(xv[1], w1v[0], a0); a1 = fmaf(xv[1], w1v[1], a1);  // k=kk0+1
                a0 = fmaf(xv[2], w2v[0], a0); a1 = fmaf(xv[2], w2v[1], a1);  // k=kk0+2
                a0 = fmaf(xv[3], w3v[0], a0); a1 = fmaf(xv[3], w3v[1], a1);  // k=kk0+3
                pacc[m][0] = a0; pacc[m][1] = a1;
            }
        }
#pragma unroll
        for (int m = 0; m < 16; ++m) { dot[m][0] += pacc[m][0]; dot[m][1] += pacc[m][1]; }
    }

    // f32 epilogue, op-for-op as numpy
    const f2 vbg = *(const f2*)(bg + c2);
    const f2 vrm = *(const f2*)(rm + c2);
    const f2 vrv = *(const f2*)(rv + c2);
    f2 vden;
    vden[0] = sqrtf(vrv[0]) + 1e-6f;
    vden[1] = sqrtf(vrv[1]) + 1e-6f;

    float imp[16][2];
#pragma unroll
    for (int m = 0; m < 16; ++m)
#pragma unroll
        for (int j = 0; j < 2; ++j) {
            const float v = fabsf(dot[m][j] + vbg[j]);
            imp[m][j] = (v - vrm[j]) / vden[j];
        }

    int kval = *kptr;
    if (kval < 1) kval = 1;
    if (kval > DIM) kval = DIM;

    // two chunks of 8 rows; one wave per row does exact kth-largest selection
    for (int ch = 0; ch < 2; ++ch) {
        __syncthreads();
#pragma unroll
        for (int m = 0; m < 8; ++m) {
            f2 v; v[0] = imp[ch * 8 + m][0]; v[1] = imp[ch * 8 + m][1];
            *(f2*)(&selbuf[m][c2]) = v;
        }
        __syncthreads();

        const int w = t >> 6;    // wave id 0..7 -> row within chunk
        const int l = t & 63;    // lane
        const size_t srow = (size_t)(row0 + ch * 8 + w);

        // monotonic u32 keys for descending f32 order; lane l owns cols 4l+256j+i
        unsigned keys[16];
#pragma unroll
        for (int j = 0; j < 4; ++j) {
            const f4 v = *(const f4*)(&selbuf[w][4 * l + 256 * j]);
#pragma unroll
            for (int i = 0; i < 4; ++i) {
                const unsigned u = __float_as_uint(v[i]);
                keys[j * 4 + i] = (u & 0x80000000u) ? ~u : (u | 0x80000000u);
            }
        }

        // bitwise search for the kth-largest key: largest T with count(>=T) >= k
        unsigned pref = 0u;
        for (int b = 31; b >= 0; --b) {
            const unsigned tt = pref | (1u << b);
            int cnt = 0;
#pragma unroll
            for (int j = 0; j < 16; ++j) cnt += (keys[j] >= tt) ? 1 : 0;
#pragma unroll
            for (int off = 32; off >= 1; off >>= 1) cnt += __shfl_xor(cnt, off, 64);
            if (cnt >= kval) pref = tt;
        }

        // mask = importance >= kth (tie-inclusive); coalesced float4 out
        const float* xr = x + srow * DIM;
        float* orow = out + srow * DIM;
#pragma unroll
        for (int j = 0; j < 4; ++j) {
            const f4 xv = *(const f4*)(xr + 4 * l + 256 * j);
            f4 o;
#pragma unroll
            for (int i = 0; i < 4; ++i) o[i] = (keys[j * 4 + i] >= pref) ? xv[i] : 0.0f;
            *(f4*)(orow + 4 * l + 256 * j) = o;
        }
    }
}

// ---------------------------------------------------------------------------
extern "C" void kernel_launch(void* const* d_in, const int* in_sizes, int n_in,
                              void* d_out, int out_size, void* d_ws, size_t ws_size,
                              hipStream_t stream) {
    const float* x  = (const float*)d_in[0];
    const float* w1 = (const float*)d_in[1];
    const float* b1 = (const float*)d_in[2];
    const float* w2 = (const float*)d_in[3];
    const float* b2 = (const float*)d_in[4];
    const float* wg = (const float*)d_in[5];
    const float* bg = (const float*)d_in[6];
    const float* rm = (const float*)d_in[7];
    const float* rv = (const float*)d_in[8];
    float* out = (float*)d_out;

    double* part = (double*)d_ws;                                  // 256*1024 f64 = 2 MB
    int* kptr = (int*)((char*)d_ws + (size_t)256 * DIM * sizeof(double));

    pool_partial<<<256, 256, 0, stream>>>(x, part);
    tiny_net<<<1, 1024, 0, stream>>>(part, w1, b1, w2, b2,
                                     out + (size_t)SEQ * DIM, kptr);
    gate_kernel<<<SEQ / BM, CBLOCK, 0, stream>>>(x, wg, bg, rm, rv, kptr, out);
}

// Round 5
// 1453.144 us; speedup vs baseline: 1.2402x; 1.2402x over previous
//
#include <hip/hip_runtime.h>
#include <cstdint>
#include <cstddef>

#define SEQ 32768
#define DIM 1024
#define HID 128
#define KMAXV 103   // int(0.1*1024)+1

using f4 = __attribute__((ext_vector_type(4))) float;

// ---------------------------------------------------------------------------
// Kernel A: per-block partial column sums of x (f64, deterministic order).
// ---------------------------------------------------------------------------
__global__ __launch_bounds__(256) void pool_partial(const float* __restrict__ x,
                                                    double* __restrict__ part) {
    const int b = blockIdx.x;
    const int t = threadIdx.x;
    const int r0 = b * 128;
    double s0 = 0.0, s1 = 0.0, s2 = 0.0, s3 = 0.0;
    for (int r = 0; r < 128; ++r) {
        const float* row = x + (size_t)(r0 + r) * DIM;
        s0 += (double)row[t];
        s1 += (double)row[t + 256];
        s2 += (double)row[t + 512];
        s3 += (double)row[t + 768];
    }
    double* p = part + (size_t)b * DIM;
    p[t] = s0; p[t + 256] = s1; p[t + 512] = s2; p[t + 768] = s3;
}

// ---------------------------------------------------------------------------
// Kernel B: finish pooling, complexity net (exact erf GELU, sigmoid), k.
// ---------------------------------------------------------------------------
__global__ __launch_bounds__(1024) void tiny_net(const double* __restrict__ part,
                                                 const float* __restrict__ w1,
                                                 const float* __restrict__ b1,
                                                 const float* __restrict__ w2,
                                                 const float* __restrict__ b2,
                                                 float* __restrict__ out_scalars,
                                                 int* __restrict__ kout) {
    __shared__ double pooled[DIM];
    __shared__ double hidv[HID];
    const int t = threadIdx.x;

    double s = 0.0;
    for (int b = 0; b < 256; ++b) s += part[(size_t)b * DIM + t];
    pooled[t] = s / (double)SEQ;
    __syncthreads();

    if (t < HID) {
        double h = (double)b1[t];
        for (int d = 0; d < DIM; ++d) h += pooled[d] * (double)w1[d * HID + t];
        h = 0.5 * h * (1.0 + erf(h * 0.70710678118654752440));
        hidv[t] = h;
    }
    __syncthreads();

    if (t == 0) {
        double z = (double)b2[0];
        for (int j = 0; j < HID; ++j) z += hidv[j] * (double)w2[j];
        double c = 1.0 / (1.0 + exp(-z));
        double ar = 0.01 + 0.09 * c;
        int k = (int)(ar * (double)DIM);  // trunc
        if (k < 1) k = 1;
        if (k > KMAXV) k = KMAXV;
        out_scalars[0] = (float)c;
        out_scalars[1] = (float)ar;
        out_scalars[2] = (float)k;
        *kout = k;
    }
}

// ---------------------------------------------------------------------------
// Kernel C: importance GEMM with numpy/OpenBLAS f32 semantics — NUMERICS
// FROZEN: per element, sequential-k fmaf within panels {384,320,320}, panel
// sums added in order ((P1+P2)+P3). Byte-identical compute order to the
// round-2/3 passing kernels.
// Structure (= round 3, proven 1133 us): 512 threads = 2 row-groups x 256
// col-threads; thread owns 8 rows x 4 CONTIGUOUS cols (dwordx4 wg loads).
// Full 16x1024 x-tile staged once to LDS (64 KB, no barriers in K-loop),
// x read via wave-broadcast ds_read_b128.
// ONE change vs round 3: __launch_bounds__(512, 2) -> VGPR cap 256, letting
// the ~125-reg working set (pacc32+dot32+wq16+8x xv f4) stay architectural
// instead of spilling through AGPR moves (~1 extra VALU op per FMA at 64
// VGPRs, the measured 2x-over-FMA-floor VALU busy time).
// ---------------------------------------------------------------------------
#define BM 16
#define CBLOCK 512

__global__ __launch_bounds__(CBLOCK, 2) void gate_kernel(const float* __restrict__ x,
                                                         const float* __restrict__ wg,
                                                         const float* __restrict__ bg,
                                                         const float* __restrict__ rm,
                                                         const float* __restrict__ rv,
                                                         const int* __restrict__ kptr,
                                                         float* __restrict__ out) {
    __shared__ float xs[BM][DIM];                 // 64 KB; selbuf aliases after GEMM
    float (*selbuf)[DIM] = (float (*)[DIM])xs;

    const int t = threadIdx.x;
    const int c4 = (t & 255) << 2;   // 4 contiguous columns c4..c4+3
    const int rg = t >> 8;           // 0 or 1 -> rows rg*8..rg*8+7
    const int row0 = blockIdx.x * BM;

    // stage full x-tile (coalesced float4)
    {
        const f4* xg = (const f4*)(x + (size_t)row0 * DIM);
        f4* xl = (f4*)xs;
        for (int i = t; i < BM * (DIM / 4); i += CBLOCK) xl[i] = xg[i];
    }
    __syncthreads();

    float dot[8][4];
#pragma unroll
    for (int m = 0; m < 8; ++m)
#pragma unroll
        for (int j = 0; j < 4; ++j) dot[m][j] = 0.0f;

    const int pb[4] = {0, 384, 704, 1024};       // OpenBLAS K-panels
    const float* xrow = &xs[rg * 8][0];
    const float* wbase = wg + c4;

    for (int p = 0; p < 3; ++p) {
        float pacc[8][4];
#pragma unroll
        for (int m = 0; m < 8; ++m)
#pragma unroll
            for (int j = 0; j < 4; ++j) pacc[m][j] = 0.0f;

        for (int kk0 = pb[p]; kk0 < pb[p + 1]; kk0 += 4) {
            const f4 wq0 = *(const f4*)(wbase + (size_t)(kk0 + 0) * DIM);
            const f4 wq1 = *(const f4*)(wbase + (size_t)(kk0 + 1) * DIM);
            const f4 wq2 = *(const f4*)(wbase + (size_t)(kk0 + 2) * DIM);
            const f4 wq3 = *(const f4*)(wbase + (size_t)(kk0 + 3) * DIM);
#pragma unroll
            for (int m = 0; m < 8; ++m) {
                const f4 xv = *(const f4*)(xrow + m * DIM + kk0);
#pragma unroll
                for (int j = 0; j < 4; ++j) {
                    float a = pacc[m][j];
                    a = fmaf(xv[0], wq0[j], a);   // k = kk0
                    a = fmaf(xv[1], wq1[j], a);   // k = kk0+1
                    a = fmaf(xv[2], wq2[j], a);   // k = kk0+2
                    a = fmaf(xv[3], wq3[j], a);   // k = kk0+3
                    pacc[m][j] = a;
                }
            }
        }
#pragma unroll
        for (int m = 0; m < 8; ++m)
#pragma unroll
            for (int j = 0; j < 4; ++j) dot[m][j] += pacc[m][j];
    }

    // f32 epilogue, op-for-op as numpy
    const f4 vbg = *(const f4*)(bg + c4);
    const f4 vrm = *(const f4*)(rm + c4);
    const f4 vrv = *(const f4*)(rv + c4);
    f4 vden;
#pragma unroll
    for (int j = 0; j < 4; ++j) vden[j] = sqrtf(vrv[j]) + 1e-6f;

    f4 imp[8];
#pragma unroll
    for (int m = 0; m < 8; ++m)
#pragma unroll
        for (int j = 0; j < 4; ++j) {
            const float v = fabsf(dot[m][j] + vbg[j]);
            imp[m][j] = (v - vrm[j]) / vden[j];
        }

    int kval = *kptr;
    if (kval < 1) kval = 1;
    if (kval > DIM) kval = DIM;

    // two chunks of 8 rows; one wave per row does exact kth-largest selection
    for (int ch = 0; ch < 2; ++ch) {
        __syncthreads();
        if (rg == ch) {
#pragma unroll
            for (int m = 0; m < 8; ++m)
                *(f4*)(&selbuf[m][c4]) = imp[m];
        }
        __syncthreads();

        const int w = t >> 6;    // wave id 0..7 -> row within chunk
        const int l = t & 63;    // lane
        const size_t srow = (size_t)(row0 + ch * 8 + w);

        // monotonic u32 keys for descending f32 order; lane l owns cols 4l+256j+i
        unsigned keys[16];
#pragma unroll
        for (int j = 0; j < 4; ++j) {
            const f4 v = *(const f4*)(&selbuf[w][4 * l + 256 * j]);
#pragma unroll
            for (int i = 0; i < 4; ++i) {
                const unsigned u = __float_as_uint(v[i]);
                keys[j * 4 + i] = (u & 0x80000000u) ? ~u : (u | 0x80000000u);
            }
        }

        // bitwise search for the kth-largest key: largest T with count(>=T) >= k
        unsigned pref = 0u;
        for (int b = 31; b >= 0; --b) {
            const unsigned tt = pref | (1u << b);
            int cnt = 0;
#pragma unroll
            for (int j = 0; j < 16; ++j) cnt += (keys[j] >= tt) ? 1 : 0;
#pragma unroll
            for (int off = 32; off >= 1; off >>= 1) cnt += __shfl_xor(cnt, off, 64);
            if (cnt >= kval) pref = tt;
        }

        // mask = importance >= kth (tie-inclusive); coalesced float4 out
        const float* xr = x + srow * DIM;
        float* orow = out + srow * DIM;
#pragma unroll
        for (int j = 0; j < 4; ++j) {
            const f4 xv = *(const f4*)(xr + 4 * l + 256 * j);
            f4 o;
#pragma unroll
            for (int i = 0; i < 4; ++i) o[i] = (keys[j * 4 + i] >= pref) ? xv[i] : 0.0f;
            *(f4*)(orow + 4 * l + 256 * j) = o;
        }
    }
}

// ---------------------------------------------------------------------------
extern "C" void kernel_launch(void* const* d_in, const int* in_sizes, int n_in,
                              void* d_out, int out_size, void* d_ws, size_t ws_size,
                              hipStream_t stream) {
    const float* x  = (const float*)d_in[0];
    const float* w1 = (const float*)d_in[1];
    const float* b1 = (const float*)d_in[2];
    const float* w2 = (const float*)d_in[3];
    const float* b2 = (const float*)d_in[4];
    const float* wg = (const float*)d_in[5];
    const float* bg = (const float*)d_in[6];
    const float* rm = (const float*)d_in[7];
    const float* rv = (const float*)d_in[8];
    float* out = (float*)d_out;

    double* part = (double*)d_ws;                                  // 256*1024 f64 = 2 MB
    int* kptr = (int*)((char*)d_ws + (size_t)256 * DIM * sizeof(double));

    pool_partial<<<256, 256, 0, stream>>>(x, part);
    tiny_net<<<1, 1024, 0, stream>>>(part, w1, b1, w2, b2,
                                     out + (size_t)SEQ * DIM, kptr);
    gate_kernel<<<SEQ / BM, CBLOCK, 0, stream>>>(x, wg, bg, rm, rv, kptr, out);
}

// Round 6
// 1210.233 us; speedup vs baseline: 1.4892x; 1.2007x over previous
//
#include <hip/hip_runtime.h>
#include <cstdint>
#include <cstddef>

#define SEQ 32768
#define DIM 1024
#define HID 128
#define KMAXV 103   // int(0.1*1024)+1

using f4 = __attribute__((ext_vector_type(4))) float;

// ---------------------------------------------------------------------------
// Kernel A: per-block partial column sums of x (f64, deterministic order).
// ---------------------------------------------------------------------------
__global__ __launch_bounds__(256) void pool_partial(const float* __restrict__ x,
                                                    double* __restrict__ part) {
    const int b = blockIdx.x;
    const int t = threadIdx.x;
    const int r0 = b * 128;
    double s0 = 0.0, s1 = 0.0, s2 = 0.0, s3 = 0.0;
    for (int r = 0; r < 128; ++r) {
        const float* row = x + (size_t)(r0 + r) * DIM;
        s0 += (double)row[t];
        s1 += (double)row[t + 256];
        s2 += (double)row[t + 512];
        s3 += (double)row[t + 768];
    }
    double* p = part + (size_t)b * DIM;
    p[t] = s0; p[t + 256] = s1; p[t + 512] = s2; p[t + 768] = s3;
}

// ---------------------------------------------------------------------------
// Kernel B: finish pooling, complexity net (exact erf GELU, sigmoid), k.
// ---------------------------------------------------------------------------
__global__ __launch_bounds__(1024) void tiny_net(const double* __restrict__ part,
                                                 const float* __restrict__ w1,
                                                 const float* __restrict__ b1,
                                                 const float* __restrict__ w2,
                                                 const float* __restrict__ b2,
                                                 float* __restrict__ out_scalars,
                                                 int* __restrict__ kout) {
    __shared__ double pooled[DIM];
    __shared__ double hidv[HID];
    const int t = threadIdx.x;

    double s = 0.0;
    for (int b = 0; b < 256; ++b) s += part[(size_t)b * DIM + t];
    pooled[t] = s / (double)SEQ;
    __syncthreads();

    if (t < HID) {
        double h = (double)b1[t];
        for (int d = 0; d < DIM; ++d) h += pooled[d] * (double)w1[d * HID + t];
        h = 0.5 * h * (1.0 + erf(h * 0.70710678118654752440));
        hidv[t] = h;
    }
    __syncthreads();

    if (t == 0) {
        double z = (double)b2[0];
        for (int j = 0; j < HID; ++j) z += hidv[j] * (double)w2[j];
        double c = 1.0 / (1.0 + exp(-z));
        double ar = 0.01 + 0.09 * c;
        int k = (int)(ar * (double)DIM);  // trunc
        if (k < 1) k = 1;
        if (k > KMAXV) k = KMAXV;
        out_scalars[0] = (float)c;
        out_scalars[1] = (float)ar;
        out_scalars[2] = (float)k;
        *kout = k;
    }
}

// ---------------------------------------------------------------------------
// Panel kernels: importance GEMM with numpy/OpenBLAS f32 semantics — NUMERICS
// FROZEN: per element, sequential-k fmaf within panels {384,320,320}, panel
// sums added in order ((P1+P2)+P3). Identical per-element op order to the
// round-2/3 passing kernels; partials passed through d_out as exact f32.
//
// Split into one kernel per K-panel so the live register set during the FMA
// loop is only pacc[8][4] (32) + 4x wq f4 (16) + xv (4) + addresses ~ 60,
// fitting the ~64-VGPR budget the allocator insists on (R3-R5 evidence:
// launch_bounds hints ignored, overflow goes to AGPR spill moves at ~1 extra
// VALU op per 2 FMAs). Small x-tiles (20-24 KB) also lift occupancy to the
// 32-wave/CU cap.
// MODE 0: out = pacc          (P1)
// MODE 1: out = out + pacc    (fl(P1+P2))
// MODE 2: dot = out + pacc, epilogue, per-row dynamic-k selection (u32 radix
//         search, tie-inclusive >=), masked x written over out in-place.
// ---------------------------------------------------------------------------
#define BM 16
#define CBLOCK 512

template<int K0, int K1, int MODE>
__global__ __launch_bounds__(CBLOCK) void panel_kernel(const float* __restrict__ x,
                                                       const float* __restrict__ wg,
                                                       const float* __restrict__ bg,
                                                       const float* __restrict__ rm,
                                                       const float* __restrict__ rv,
                                                       const int* __restrict__ kptr,
                                                       float* __restrict__ out) {
    constexpr int PK = K1 - K0;
    constexpr int PK4 = PK / 4;
    constexpr int LDSF = (MODE == 2 && 8 * DIM > BM * PK) ? 8 * DIM : BM * PK;
    __shared__ float lbuf[LDSF];

    const int t = threadIdx.x;
    const int c4 = (t & 255) << 2;   // 4 contiguous columns c4..c4+3
    const int rg = t >> 8;           // 0 or 1 -> rows rg*8..rg*8+7
    const int row0 = blockIdx.x * BM;

    // stage x slice [row0:row0+16][K0:K1] (coalesced float4)
    {
        f4* xl = (f4*)lbuf;
        for (int i = t; i < BM * PK4; i += CBLOCK) {
            const int r = i / PK4, cc = i - r * PK4;
            xl[i] = *(const f4*)(x + (size_t)(row0 + r) * DIM + K0 + 4 * cc);
        }
    }
    __syncthreads();

    float pacc[8][4];
#pragma unroll
    for (int m = 0; m < 8; ++m)
#pragma unroll
        for (int j = 0; j < 4; ++j) pacc[m][j] = 0.0f;

    const float* xrow = lbuf + rg * 8 * PK;
    const float* wbase = wg + c4;

    for (int kk0 = K0; kk0 < K1; kk0 += 4) {
        const f4 wq0 = *(const f4*)(wbase + (size_t)(kk0 + 0) * DIM);
        const f4 wq1 = *(const f4*)(wbase + (size_t)(kk0 + 1) * DIM);
        const f4 wq2 = *(const f4*)(wbase + (size_t)(kk0 + 2) * DIM);
        const f4 wq3 = *(const f4*)(wbase + (size_t)(kk0 + 3) * DIM);
#pragma unroll
        for (int m = 0; m < 8; ++m) {
            const f4 xv = *(const f4*)(xrow + m * PK + (kk0 - K0));
#pragma unroll
            for (int j = 0; j < 4; ++j) {
                float a = pacc[m][j];
                a = fmaf(xv[0], wq0[j], a);   // k = kk0
                a = fmaf(xv[1], wq1[j], a);   // k = kk0+1
                a = fmaf(xv[2], wq2[j], a);   // k = kk0+2
                a = fmaf(xv[3], wq3[j], a);   // k = kk0+3
                pacc[m][j] = a;
            }
        }
    }

    if constexpr (MODE == 0) {
#pragma unroll
        for (int m = 0; m < 8; ++m) {
            f4 v; v[0] = pacc[m][0]; v[1] = pacc[m][1]; v[2] = pacc[m][2]; v[3] = pacc[m][3];
            *(f4*)(out + (size_t)(row0 + rg * 8 + m) * DIM + c4) = v;
        }
        return;
    } else if constexpr (MODE == 1) {
#pragma unroll
        for (int m = 0; m < 8; ++m) {
            float* op = out + (size_t)(row0 + rg * 8 + m) * DIM + c4;
            f4 d = *(const f4*)op;
#pragma unroll
            for (int j = 0; j < 4; ++j) d[j] = d[j] + pacc[m][j];  // fl(P1+P2)
            *(f4*)op = d;
        }
        return;
    } else {
        // MODE 2: finalize dot, epilogue, selection, masked write
        float dot[8][4];
#pragma unroll
        for (int m = 0; m < 8; ++m) {
            const float* op = out + (size_t)(row0 + rg * 8 + m) * DIM + c4;
            const f4 d = *(const f4*)op;
#pragma unroll
            for (int j = 0; j < 4; ++j) dot[m][j] = d[j] + pacc[m][j];  // fl((P1+P2)+P3)
        }

        // f32 epilogue, op-for-op as numpy
        const f4 vbg = *(const f4*)(bg + c4);
        const f4 vrm = *(const f4*)(rm + c4);
        const f4 vrv = *(const f4*)(rv + c4);
        f4 vden;
#pragma unroll
        for (int j = 0; j < 4; ++j) vden[j] = sqrtf(vrv[j]) + 1e-6f;

        f4 imp[8];
#pragma unroll
        for (int m = 0; m < 8; ++m)
#pragma unroll
            for (int j = 0; j < 4; ++j) {
                const float v = fabsf(dot[m][j] + vbg[j]);
                imp[m][j] = (v - vrm[j]) / vden[j];
            }

        int kval = *kptr;
        if (kval < 1) kval = 1;
        if (kval > DIM) kval = DIM;

        float (*selbuf)[DIM] = (float (*)[DIM])lbuf;

        // two chunks of 8 rows; one wave per row does exact kth-largest selection
        for (int ch = 0; ch < 2; ++ch) {
            __syncthreads();
            if (rg == ch) {
#pragma unroll
                for (int m = 0; m < 8; ++m)
                    *(f4*)(&selbuf[m][c4]) = imp[m];
            }
            __syncthreads();

            const int w = t >> 6;    // wave id 0..7 -> row within chunk
            const int l = t & 63;    // lane
            const size_t srow = (size_t)(row0 + ch * 8 + w);

            // monotonic u32 keys for descending f32 order
            unsigned keys[16];
#pragma unroll
            for (int j = 0; j < 4; ++j) {
                const f4 v = *(const f4*)(&selbuf[w][4 * l + 256 * j]);
#pragma unroll
                for (int i = 0; i < 4; ++i) {
                    const unsigned u = __float_as_uint(v[i]);
                    keys[j * 4 + i] = (u & 0x80000000u) ? ~u : (u | 0x80000000u);
                }
            }

            // bitwise search for the kth-largest key: largest T with count(>=T) >= k
            unsigned pref = 0u;
            for (int b = 31; b >= 0; --b) {
                const unsigned tt = pref | (1u << b);
                int cnt = 0;
#pragma unroll
                for (int j = 0; j < 16; ++j) cnt += (keys[j] >= tt) ? 1 : 0;
#pragma unroll
                for (int off = 32; off >= 1; off >>= 1) cnt += __shfl_xor(cnt, off, 64);
                if (cnt >= kval) pref = tt;
            }

            // mask = importance >= kth (tie-inclusive); coalesced float4 out
            const float* xr = x + srow * DIM;
            float* orow = out + srow * DIM;
#pragma unroll
            for (int j = 0; j < 4; ++j) {
                const f4 xv = *(const f4*)(xr + 4 * l + 256 * j);
                f4 o;
#pragma unroll
                for (int i = 0; i < 4; ++i) o[i] = (keys[j * 4 + i] >= pref) ? xv[i] : 0.0f;
                *(f4*)(orow + 4 * l + 256 * j) = o;
            }
        }
    }
}

// ---------------------------------------------------------------------------
extern "C" void kernel_launch(void* const* d_in, const int* in_sizes, int n_in,
                              void* d_out, int out_size, void* d_ws, size_t ws_size,
                              hipStream_t stream) {
    const float* x  = (const float*)d_in[0];
    const float* w1 = (const float*)d_in[1];
    const float* b1 = (const float*)d_in[2];
    const float* w2 = (const float*)d_in[3];
    const float* b2 = (const float*)d_in[4];
    const float* wg = (const float*)d_in[5];
    const float* bg = (const float*)d_in[6];
    const float* rm = (const float*)d_in[7];
    const float* rv = (const float*)d_in[8];
    float* out = (float*)d_out;

    double* part = (double*)d_ws;                                  // 256*1024 f64 = 2 MB
    int* kptr = (int*)((char*)d_ws + (size_t)256 * DIM * sizeof(double));

    pool_partial<<<256, 256, 0, stream>>>(x, part);
    tiny_net<<<1, 1024, 0, stream>>>(part, w1, b1, w2, b2,
                                     out + (size_t)SEQ * DIM, kptr);
    panel_kernel<0,   384,  0><<<SEQ / BM, CBLOCK, 0, stream>>>(x, wg, bg, rm, rv, kptr, out);
    panel_kernel<384, 704,  1><<<SEQ / BM, CBLOCK, 0, stream>>>(x, wg, bg, rm, rv, kptr, out);
    panel_kernel<704, 1024, 2><<<SEQ / BM, CBLOCK, 0, stream>>>(x, wg, bg, rm, rv, kptr, out);
}